// Round 4
// baseline (591.374 us; speedup 1.0000x reference)
//
#include <hip/hip_runtime.h>

#define NHID 128
#define BM   128
#define LDE  136   // 128 + 8 pad: row stride 272 B = 17*16 B (odd multiple of 16)

typedef __attribute__((ext_vector_type(8))) short short8;
typedef __attribute__((ext_vector_type(4))) float f32x4;
typedef __attribute__((ext_vector_type(4))) unsigned short ushort4v;

__device__ inline unsigned short f2bf(float f) {
    unsigned int u = __float_as_uint(f);
    u += 0x7fffu + ((u >> 16) & 1u);   // round-to-nearest-even
    return (unsigned short)(u >> 16);
}
__device__ inline float bf2f(unsigned short h) {
    return __uint_as_float(((unsigned int)h) << 16);
}

// ---- prep: convert/transpose weights to bf16, detect int64 edge_index ----
// wtp [256][128]: row f (0..127) = W1[:,f], row 128+f = W2[:,f]  (i.e. [out_feat][k])
// wt3 [128][128]: W3 as [out_feat][k]     wte [128][128]: W_edge as [out_feat][k]
__global__ void prep_kernel(const float* __restrict__ Wm, const float* __restrict__ We,
                            const int* __restrict__ eidx_raw,
                            unsigned short* __restrict__ wtp,
                            unsigned short* __restrict__ wt3,
                            unsigned short* __restrict__ wte,
                            int* __restrict__ flag) {
    int i = blockIdx.x * 256 + threadIdx.x;
    if (i < 256 * NHID) {
        int nn = i >> 7, k = i & 127;
        float v = (nn < 128) ? Wm[k * NHID + nn] : Wm[(128 + k) * NHID + (nn - 128)];
        wtp[i] = f2bf(v);
    }
    if (i < NHID * NHID) {
        int n = i >> 7, k = i & 127;
        wt3[i] = f2bf(Wm[(256 + k) * NHID + n]);
        wte[i] = f2bf(We[k * NHID + n]);
    }
    if (blockIdx.x == 0) {
        __shared__ int nz;
        if (threadIdx.x == 0) nz = 0;
        __syncthreads();
        if (threadIdx.x < 64) {
            if (eidx_raw[threadIdx.x * 2 + 1] != 0) atomicAdd(&nz, 1);
        }
        __syncthreads();
        if (threadIdx.x == 0) flag[0] = (nz == 0) ? 1 : 0;   // 1 => int64
    }
}

// ---- node projection (transposed MFMA): xp[n][0:128]=x[n]@W1, [128:256]=x[n]@W2 ----
// D[feat][node] = W[feat][k] * x[node][k]; C-layout: lane=node, regs=4 consecutive feats
__global__ __launch_bounds__(256, 4) void proj_kernel(
    const float* __restrict__ x, const unsigned short* __restrict__ wtp,
    unsigned short* __restrict__ xp, int N)
{
    __shared__ __align__(16) unsigned short sX[BM * LDE];

    const int tid  = threadIdx.x;
    const int lane = tid & 63;
    const int wave = tid >> 6;
    const int wm   = wave >> 1, wn = wave & 1;
    const int l15  = lane & 15, l4 = lane >> 4;
    const int n0   = blockIdx.x * BM;
    const int half = blockIdx.y;          // 0: W1, 1: W2

    // stage x rows fp32 -> bf16
    const int erow = tid >> 4, kg = tid & 15;
    #pragma unroll
    for (int p = 0; p < 8; ++p) {
        int el = p * 16 + erow;
        int n  = n0 + el; if (n >= N) n = N - 1;
        const float4* sp = (const float4*)(x + (size_t)n * NHID + kg * 8);
        float4 f0 = sp[0], f1 = sp[1];
        short8 hv;
        hv[0] = (short)f2bf(f0.x); hv[1] = (short)f2bf(f0.y);
        hv[2] = (short)f2bf(f0.z); hv[3] = (short)f2bf(f0.w);
        hv[4] = (short)f2bf(f1.x); hv[5] = (short)f2bf(f1.y);
        hv[6] = (short)f2bf(f1.z); hv[7] = (short)f2bf(f1.w);
        *(short8*)&sX[el * LDE + kg * 8] = hv;
    }
    __syncthreads();

    f32x4 acc[4][4];   // [mt = feat-block][nt = node-block]
    #pragma unroll
    for (int mt = 0; mt < 4; ++mt)
        #pragma unroll
        for (int nt = 0; nt < 4; ++nt) acc[mt][nt] = (f32x4){0.f,0.f,0.f,0.f};

    const unsigned short* wb = wtp + half * NHID * NHID;
    #pragma unroll
    for (int kk = 0; kk < 4; ++kk) {
        short8 af[4], bfr[4];
        #pragma unroll
        for (int mt = 0; mt < 4; ++mt)
            af[mt] = *(const short8*)(wb + (wm * 64 + mt * 16 + l15) * NHID + kk * 32 + l4 * 8);
        #pragma unroll
        for (int nt = 0; nt < 4; ++nt)
            bfr[nt] = *(const short8*)(&sX[(wn * 64 + nt * 16 + l15) * LDE + kk * 32 + l4 * 8]);
        #pragma unroll
        for (int mt = 0; mt < 4; ++mt)
            #pragma unroll
            for (int nt = 0; nt < 4; ++nt)
                acc[mt][nt] = __builtin_amdgcn_mfma_f32_16x16x32_bf16(
                    af[mt], bfr[nt], acc[mt][nt], 0, 0, 0);
    }

    // write: lane owns node (nt,l15), feats wm*64+mt*16+l4*4+0..3 -> ushort4 stores
    #pragma unroll
    for (int nt = 0; nt < 4; ++nt) {
        int n = n0 + wn * 64 + nt * 16 + l15;
        if (n < N) {
            #pragma unroll
            for (int mt = 0; mt < 4; ++mt) {
                ushort4v v;
                #pragma unroll
                for (int r = 0; r < 4; ++r) v[r] = f2bf(acc[mt][nt][r]);
                *(ushort4v*)(xp + (size_t)n * 256 + half * NHID + wm * 64 + mt * 16 + l4 * 4) = v;
            }
        }
    }
}

// ---- main: per 128-edge tile, transposed MFMA (lane=edge, regs=4 consecutive feats) ----
__global__ __launch_bounds__(256, 4) void edge_conv_kernel(
    const float* __restrict__ eattr,
    const int* __restrict__ ip,
    const float* __restrict__ bmsg, const float* __restrict__ bedge,
    const unsigned short* __restrict__ wt3,
    const unsigned short* __restrict__ wte,
    const unsigned short* __restrict__ xp,
    const int* __restrict__ flag,
    float* __restrict__ out, int E)
{
    __shared__ __align__(16) unsigned short sEA[BM * LDE];  // 34816 B
    __shared__ int sIdx[2 * BM];                            // 1024 B

    const int tid  = threadIdx.x;
    const int lane = tid & 63;
    const int wave = tid >> 6;
    const int wm   = wave >> 1, wn = wave & 1;
    const int l15  = lane & 15, l4 = lane >> 4;
    const int e0   = blockIdx.x * BM;
    const int is64 = flag[0];

    // edge indices (low words if int64)
    {
        int t = tid;
        if (t < BM) {
            int e = e0 + t; if (e >= E) e = E - 1;
            sIdx[t] = is64 ? ip[2 * (long long)e] : ip[e];
        } else {
            int e = e0 + (t - BM); if (e >= E) e = E - 1;
            long long off = (long long)E + e;
            sIdx[t] = is64 ? ip[2 * off] : ip[off];
        }
    }

    // stage edge_attr fp32 -> bf16 (contiguous 64 KB block read)
    const int erow = tid >> 4, kg = tid & 15;
    #pragma unroll
    for (int p = 0; p < 8; ++p) {
        int el = p * 16 + erow;
        int e  = e0 + el; if (e >= E) e = E - 1;
        const float4* sp = (const float4*)(eattr + (size_t)e * NHID + kg * 8);
        float4 f0 = sp[0], f1 = sp[1];
        short8 hv;
        hv[0] = (short)f2bf(f0.x); hv[1] = (short)f2bf(f0.y);
        hv[2] = (short)f2bf(f0.z); hv[3] = (short)f2bf(f0.w);
        hv[4] = (short)f2bf(f1.x); hv[5] = (short)f2bf(f1.y);
        hv[6] = (short)f2bf(f1.z); hv[7] = (short)f2bf(f1.w);
        *(short8*)&sEA[el * LDE + kg * 8] = hv;
    }
    __syncthreads();

    f32x4 acc[4][4];   // [mt = feat-block][nt = edge-block]
    #pragma unroll
    for (int mt = 0; mt < 4; ++mt)
        #pragma unroll
        for (int nt = 0; nt < 4; ++nt) acc[mt][nt] = (f32x4){0.f,0.f,0.f,0.f};

    // GEMM1': D = W3 * eattr^T   (A = wt3 rows, B = sEA rows; K = 128)
    #pragma unroll
    for (int kk = 0; kk < 4; ++kk) {
        short8 af[4], bfr[4];
        #pragma unroll
        for (int mt = 0; mt < 4; ++mt)
            af[mt] = *(const short8*)(wt3 + (wm * 64 + mt * 16 + l15) * NHID + kk * 32 + l4 * 8);
        #pragma unroll
        for (int nt = 0; nt < 4; ++nt)
            bfr[nt] = *(const short8*)(&sEA[(wn * 64 + nt * 16 + l15) * LDE + kk * 32 + l4 * 8]);
        #pragma unroll
        for (int mt = 0; mt < 4; ++mt)
            #pragma unroll
            for (int nt = 0; nt < 4; ++nt)
                acc[mt][nt] = __builtin_amdgcn_mfma_f32_16x16x32_bf16(
                    af[mt], bfr[nt], acc[mt][nt], 0, 0, 0);
    }
    __syncthreads();   // all waves done reading sEA before epilogue rewrites it

    // epilogue 1: ea = edge_attr + relu(acc + b_msg + Xp1[row] + Xp2[col])
    // all accesses vectorized: ushort4 gathers, ushort4 LDS rmw
    {
        f32x4 bm4[4];
        #pragma unroll
        for (int mt = 0; mt < 4; ++mt)
            bm4[mt] = *(const f32x4*)(bmsg + wm * 64 + mt * 16 + l4 * 4);
        #pragma unroll
        for (int nt = 0; nt < 4; ++nt) {
            int eL = wn * 64 + nt * 16 + l15;
            int nr = sIdx[eL];
            int nc = sIdx[BM + eL];
            ushort4v p1[4], p2[4];
            #pragma unroll
            for (int mt = 0; mt < 4; ++mt)
                p1[mt] = *(const ushort4v*)(xp + (size_t)nr * 256 + wm * 64 + mt * 16 + l4 * 4);
            #pragma unroll
            for (int mt = 0; mt < 4; ++mt)
                p2[mt] = *(const ushort4v*)(xp + (size_t)nc * 256 + 128 + wm * 64 + mt * 16 + l4 * 4);
            #pragma unroll
            for (int mt = 0; mt < 4; ++mt) {
                int fb = wm * 64 + mt * 16 + l4 * 4;
                ushort4v old = *(ushort4v*)(&sEA[eL * LDE + fb]);
                ushort4v nw;
                #pragma unroll
                for (int r = 0; r < 4; ++r) {
                    float m = acc[mt][nt][r] + bm4[mt][r]
                            + bf2f(p1[mt][r]) + bf2f(p2[mt][r]);
                    m = fmaxf(m, 0.f);
                    nw[r] = f2bf(bf2f(old[r]) + m);
                    acc[mt][nt][r] = 0.f;
                }
                *(ushort4v*)(&sEA[eL * LDE + fb]) = nw;
            }
        }
    }
    __syncthreads();

    // GEMM2: D = W_edge * ea^T   (K = 128)
    #pragma unroll
    for (int kk = 0; kk < 4; ++kk) {
        short8 af[4], bfr[4];
        #pragma unroll
        for (int mt = 0; mt < 4; ++mt)
            af[mt] = *(const short8*)(wte + (wm * 64 + mt * 16 + l15) * NHID + kk * 32 + l4 * 8);
        #pragma unroll
        for (int nt = 0; nt < 4; ++nt)
            bfr[nt] = *(const short8*)(&sEA[(wn * 64 + nt * 16 + l15) * LDE + kk * 32 + l4 * 8]);
        #pragma unroll
        for (int mt = 0; mt < 4; ++mt)
            #pragma unroll
            for (int nt = 0; nt < 4; ++nt)
                acc[mt][nt] = __builtin_amdgcn_mfma_f32_16x16x32_bf16(
                    af[mt], bfr[nt], acc[mt][nt], 0, 0, 0);
    }

    // epilogue 2: out = relu(acc + b_edge), float4 stores (4 consecutive feats/lane)
    {
        f32x4 be4[4];
        #pragma unroll
        for (int mt = 0; mt < 4; ++mt)
            be4[mt] = *(const f32x4*)(bedge + wm * 64 + mt * 16 + l4 * 4);
        #pragma unroll
        for (int nt = 0; nt < 4; ++nt) {
            int eL = wn * 64 + nt * 16 + l15;
            int e  = e0 + eL;
            if (e < E) {
                #pragma unroll
                for (int mt = 0; mt < 4; ++mt) {
                    int fb = wm * 64 + mt * 16 + l4 * 4;
                    f32x4 v;
                    #pragma unroll
                    for (int r = 0; r < 4; ++r)
                        v[r] = fmaxf(acc[mt][nt][r] + be4[mt][r], 0.f);
                    *(f32x4*)(out + (size_t)e * NHID + fb) = v;
                }
            }
        }
    }
}

extern "C" void kernel_launch(void* const* d_in, const int* in_sizes, int n_in,
                              void* d_out, int out_size, void* d_ws, size_t ws_size,
                              hipStream_t stream) {
    const float* x     = (const float*)d_in[0];
    const float* eattr = (const float*)d_in[1];
    const int*   eidx  = (const int*)d_in[2];
    const float* Wm    = (const float*)d_in[3];
    const float* bm    = (const float*)d_in[4];
    const float* We    = (const float*)d_in[5];
    const float* be    = (const float*)d_in[6];
    float* out = (float*)d_out;

    const int N = in_sizes[0] / NHID;
    const int E = in_sizes[2] / 2;

    unsigned short* wtp = (unsigned short*)d_ws;        // 256*128
    unsigned short* wt3 = wtp + 256 * NHID;             // 128*128
    unsigned short* wte = wt3 + NHID * NHID;            // 128*128
    int* flag = (int*)(wte + NHID * NHID);
    unsigned short* xp  = (unsigned short*)(flag + 4);  // N*256 bf16 (~51 MB)

    prep_kernel<<<(256 * NHID + 255) / 256, 256, 0, stream>>>(Wm, We, eidx, wtp, wt3, wte, flag);

    dim3 pgrid((N + BM - 1) / BM, 2);
    proj_kernel<<<pgrid, 256, 0, stream>>>(x, wtp, xp, N);

    int nblocks = (E + BM - 1) / BM;
    edge_conv_kernel<<<nblocks, 256, 0, stream>>>(eattr, eidx, bm, be,
                                                  wt3, wte, xp, flag, out, E);
}